// Round 4
// baseline (214.216 us; speedup 1.0000x reference)
//
#include <hip/hip_runtime.h>
#include <math.h>

// Fixed problem dims from setup_inputs()
#define BATCH 2
#define C 64
#define HIN 128
#define WIN 128
#define HW (HIN * WIN)
#define OH 256
#define OW 256
#define SCALE 2.0f

#define BLK 128          // threads per block
#define LDS_STRIDE 68    // floats per thread row (17 dwordx4 -> 16B aligned, bank-spread)

// Round-4 structure:
//  - h1 (the 64-wide hidden activation) lives in 64 NAMED SCALARS, macro
//    generated. Rounds 1-3 proved clang leaves a 64-float constant-indexed
//    array alloca in scratch (VGPR_Count=48/72 with VALUBusy<36%). Named
//    scalars cannot be scratch-resident; __launch_bounds__(128,2) caps
//    VGPR at 256 which comfortably fits h1(64)+staging(~40).
//  - fea0 goes to LDS as a per-thread backing row (stride 68 floats,
//    ds_read/write_b128, no barriers needed: each thread touches only its
//    own row). Expand reads it back instead of re-sampling global.
//  - Grid 1024 blocks of 128 -> 4 blocks/CU = 8 waves/CU (grid-limited,
//    same as rounds 1-3); latency hidden by in-loop prefetch ILP.

#define REP64(M) \
  M(0)  M(1)  M(2)  M(3)  M(4)  M(5)  M(6)  M(7)  \
  M(8)  M(9)  M(10) M(11) M(12) M(13) M(14) M(15) \
  M(16) M(17) M(18) M(19) M(20) M(21) M(22) M(23) \
  M(24) M(25) M(26) M(27) M(28) M(29) M(30) M(31) \
  M(32) M(33) M(34) M(35) M(36) M(37) M(38) M(39) \
  M(40) M(41) M(42) M(43) M(44) M(45) M(46) M(47) \
  M(48) M(49) M(50) M(51) M(52) M(53) M(54) M(55) \
  M(56) M(57) M(58) M(59) M(60) M(61) M(62) M(63)

__global__ __launch_bounds__(BLK, 2) void scab_kernel(
    const float* __restrict__ x,    // (B, C, HIN, WIN)
    const float* __restrict__ wcm,  // weight_compress (4, 8, 64)
    const float* __restrict__ wex,  // weight_expand   (4, 64, 8)
    const float* __restrict__ w1,   // (64, 68)
    const float* __restrict__ b1,   // (64)
    const float* __restrict__ w2,   // (64, 64)
    const float* __restrict__ b2,   // (64)
    const float* __restrict__ wr,   // (4, 64)
    const float* __restrict__ br,   // (4)
    const float* __restrict__ wo,   // (2, 64)
    const float* __restrict__ bo,   // (2)
    float* __restrict__ out)        // (B, C, OH, OW)
{
    __shared__ __align__(16) float lds[BLK * LDS_STRIDE];  // fea0 backing store

    const int tid = threadIdx.x;
    const int p  = blockIdx.x * BLK + tid;
    const int ox = p & (OW - 1);
    const int oy = (p >> 8) & (OH - 1);
    const int bb = p >> 16;

    // ---- coords channels (match reference exactly) ----
    const float c01 = 1.0f / SCALE;
    const float fh = (oy + 0.5f) / SCALE;
    const float coor_h = fh - floorf(fh + 0.001f) - 0.5f;
    const float fw = (ox + 0.5f) / SCALE;
    const float coor_w = fw - floorf(fw + 0.001f) - 0.5f;

    // ---- base grid (make_grid without offset) ----
    const float gx = ((ox + 0.5f) / SCALE - 0.5f) * (2.0f / (WIN - 1)) - 1.0f;
    const float gy = ((oy + 0.5f) / SCALE - 0.5f) * (2.0f / (HIN - 1)) - 1.0f;

    const float* __restrict__ xb = x + bb * (C * HW);

    // ---- sampling-1 indices & bilinear weights ----
    int i00, i10, i01, i11;
    float w00, w10, w01, w11;
    {
        const float fx = ((gx + 1.0f) * WIN - 1.0f) * 0.5f;
        const float fy = ((gy + 1.0f) * HIN - 1.0f) * 0.5f;
        const float x0 = floorf(fx), y0 = floorf(fy);
        const float wx1 = fx - x0, wx0 = 1.0f - wx1;
        const float wy1 = fy - y0, wy0 = 1.0f - wy1;
        const float x1 = x0 + 1.0f, y1 = y0 + 1.0f;
        const bool vx0 = (x0 >= 0.0f) && (x0 <= (float)(WIN - 1));
        const bool vx1 = (x1 >= 0.0f) && (x1 <= (float)(WIN - 1));
        const bool vy0 = (y0 >= 0.0f) && (y0 <= (float)(HIN - 1));
        const bool vy1 = (y1 >= 0.0f) && (y1 <= (float)(HIN - 1));
        const int xi0 = (int)fminf(fmaxf(x0, 0.0f), (float)(WIN - 1));
        const int xi1 = (int)fminf(fmaxf(x1, 0.0f), (float)(WIN - 1));
        const int yi0 = (int)fminf(fmaxf(y0, 0.0f), (float)(HIN - 1));
        const int yi1 = (int)fminf(fmaxf(y1, 0.0f), (float)(HIN - 1));
        w00 = wx0 * wy0 * ((vx0 && vy0) ? 1.0f : 0.0f);
        w10 = wx1 * wy0 * ((vx1 && vy0) ? 1.0f : 0.0f);
        w01 = wx0 * wy1 * ((vx0 && vy1) ? 1.0f : 0.0f);
        w11 = wx1 * wy1 * ((vx1 && vy1) ? 1.0f : 0.0f);
        i00 = yi0 * WIN + xi0;
        i10 = yi0 * WIN + xi1;
        i01 = yi1 * WIN + xi0;
        i11 = yi1 * WIN + xi1;
    }

    // ===== h1 as 64 named scalars, init = bias + coord terms =====
#define DECLH(i) float h_##i;
    REP64(DECLH)
#undef DECLH
#define INITH(i) h_##i = fmaf(w1[(i)*(C+4)+3], coor_w,                         \
                     fmaf(w1[(i)*(C+4)+2], coor_h,                             \
                     fmaf(w1[(i)*(C+4)+1], c01,                                \
                     fmaf(w1[(i)*(C+4)+0], c01, b1[(i)]))));
    REP64(INITH)
#undef INITH

    // ===== fused sampling-1 + conv1 (accumulator form, 4-channel chunks) =====
    {
        float lc[16], ln[16];
        #pragma unroll
        for (int k = 0; k < 4; ++k) {
            const float* __restrict__ xc = xb + k * HW;
            lc[4*k+0] = xc[i00]; lc[4*k+1] = xc[i10];
            lc[4*k+2] = xc[i01]; lc[4*k+3] = xc[i11];
        }
        for (int cc = 0; cc < C; cc += 4) {
            const int cn = (cc < C - 4) ? (cc + 4) : cc;
            #pragma unroll
            for (int k = 0; k < 4; ++k) {
                const float* __restrict__ xc = xb + (cn + k) * HW;
                ln[4*k+0] = xc[i00]; ln[4*k+1] = xc[i10];
                ln[4*k+2] = xc[i01]; ln[4*k+3] = xc[i11];
            }
            const float pf0 = lc[0]*w00  + lc[1]*w10  + lc[2]*w01  + lc[3]*w11;
            const float pf1 = lc[4]*w00  + lc[5]*w10  + lc[6]*w01  + lc[7]*w11;
            const float pf2 = lc[8]*w00  + lc[9]*w10  + lc[10]*w01 + lc[11]*w11;
            const float pf3 = lc[12]*w00 + lc[13]*w10 + lc[14]*w01 + lc[15]*w11;
#define CONV1(i) h_##i = fmaf(w1[(i)*(C+4)+4+cc+0], pf0,                       \
                     fmaf(w1[(i)*(C+4)+4+cc+1], pf1,                           \
                     fmaf(w1[(i)*(C+4)+4+cc+2], pf2,                           \
                     fmaf(w1[(i)*(C+4)+4+cc+3], pf3, h_##i))));
            // NOTE: nesting reorders the 4 adds; fp32 assoc noise << threshold
            REP64(CONV1)
#undef CONV1
            #pragma unroll
            for (int k = 0; k < 16; ++k) lc[k] = ln[k];
        }
    }
#define RELUH(i) h_##i = fmaxf(h_##i, 0.0f);
    REP64(RELUH)
#undef RELUH

    // ===== conv2 + heads (rolled o; 4 independent FMA chains over named h) =====
    float offx = bo[0], offy = bo[1];
    float z0 = br[0], z1 = br[1], z2 = br[2], z3 = br[3];
    for (int o = 0; o < C; ++o) {
        const float* __restrict__ wrow = w2 + o * C;   // contiguous row
        float a0 = b2[o], a1 = 0.0f, a2 = 0.0f, a3 = 0.0f;
#define C2G(i0,i1,i2,i3)                                                       \
        a0 = fmaf(wrow[i0], h_##i0, a0); a1 = fmaf(wrow[i1], h_##i1, a1);      \
        a2 = fmaf(wrow[i2], h_##i2, a2); a3 = fmaf(wrow[i3], h_##i3, a3);
        C2G(0,1,2,3)     C2G(4,5,6,7)     C2G(8,9,10,11)   C2G(12,13,14,15)
        C2G(16,17,18,19) C2G(20,21,22,23) C2G(24,25,26,27) C2G(28,29,30,31)
        C2G(32,33,34,35) C2G(36,37,38,39) C2G(40,41,42,43) C2G(44,45,46,47)
        C2G(48,49,50,51) C2G(52,53,54,55) C2G(56,57,58,59) C2G(60,61,62,63)
#undef C2G
        const float e = fmaxf((a0 + a1) + (a2 + a3), 0.0f);
        offx = fmaf(wo[o],         e, offx);
        offy = fmaf(wo[C + o],     e, offy);
        z0   = fmaf(wr[o],         e, z0);
        z1   = fmaf(wr[C + o],     e, z1);
        z2   = fmaf(wr[2 * C + o], e, z2);
        z3   = fmaf(wr[3 * C + o], e, z3);
    }

    const float rg0 = 1.0f / (1.0f + __expf(-z0));
    const float rg1 = 1.0f / (1.0f + __expf(-z1));
    const float rg2 = 1.0f / (1.0f + __expf(-z2));
    const float rg3 = 1.0f / (1.0f + __expf(-z3));

    // ---- sampling-2 indices & weights (with offset) ----
    int j00, j10, j01, j11;
    float v00, v10, v01, v11;
    {
        const float ix2 = gx + offx * (2.0f / (WIN - 1));
        const float iy2 = gy + offy * (2.0f / (HIN - 1));
        const float fx = ((ix2 + 1.0f) * WIN - 1.0f) * 0.5f;
        const float fy = ((iy2 + 1.0f) * HIN - 1.0f) * 0.5f;
        const float x0 = floorf(fx), y0 = floorf(fy);
        const float wx1 = fx - x0, wx0 = 1.0f - wx1;
        const float wy1 = fy - y0, wy0 = 1.0f - wy1;
        const float x1 = x0 + 1.0f, y1 = y0 + 1.0f;
        const bool vx0 = (x0 >= 0.0f) && (x0 <= (float)(WIN - 1));
        const bool vx1 = (x1 >= 0.0f) && (x1 <= (float)(WIN - 1));
        const bool vy0 = (y0 >= 0.0f) && (y0 <= (float)(HIN - 1));
        const bool vy1 = (y1 >= 0.0f) && (y1 <= (float)(HIN - 1));
        const int xi0 = (int)fminf(fmaxf(x0, 0.0f), (float)(WIN - 1));
        const int xi1 = (int)fminf(fmaxf(x1, 0.0f), (float)(WIN - 1));
        const int yi0 = (int)fminf(fmaxf(y0, 0.0f), (float)(HIN - 1));
        const int yi1 = (int)fminf(fmaxf(y1, 0.0f), (float)(HIN - 1));
        v00 = wx0 * wy0 * ((vx0 && vy0) ? 1.0f : 0.0f);
        v10 = wx1 * wy0 * ((vx1 && vy0) ? 1.0f : 0.0f);
        v01 = wx0 * wy1 * ((vx0 && vy1) ? 1.0f : 0.0f);
        v11 = wx1 * wy1 * ((vx1 && vy1) ? 1.0f : 0.0f);
        j00 = yi0 * WIN + xi0;
        j10 = yi0 * WIN + xi1;
        j01 = yi1 * WIN + xi0;
        j11 = yi1 * WIN + xi1;
    }

    // ===== fused sampling-2 + compress; fea0 chunk -> LDS (b128) =====
    float comp[8];
    #pragma unroll
    for (int d = 0; d < 8; ++d) comp[d] = 0.0f;
    {
        float* __restrict__ myrow = lds + tid * LDS_STRIDE;
        float lc[16], ln[16];
        #pragma unroll
        for (int k = 0; k < 4; ++k) {
            const float* __restrict__ xc = xb + k * HW;
            lc[4*k+0] = xc[j00]; lc[4*k+1] = xc[j10];
            lc[4*k+2] = xc[j01]; lc[4*k+3] = xc[j11];
        }
        for (int cc = 0; cc < C; cc += 4) {
            const int cn = (cc < C - 4) ? (cc + 4) : cc;
            #pragma unroll
            for (int k = 0; k < 4; ++k) {
                const float* __restrict__ xc = xb + (cn + k) * HW;
                ln[4*k+0] = xc[j00]; ln[4*k+1] = xc[j10];
                ln[4*k+2] = xc[j01]; ln[4*k+3] = xc[j11];
            }
            float fc[4];
            #pragma unroll
            for (int k = 0; k < 4; ++k)
                fc[k] = lc[4*k]*v00 + lc[4*k+1]*v10 + lc[4*k+2]*v01 + lc[4*k+3]*v11;
            *(float4*)(myrow + cc) = make_float4(fc[0], fc[1], fc[2], fc[3]);  // ds_write_b128
            #pragma unroll
            for (int k = 0; k < 4; ++k) {
                const int c = cc + k;
                const float s0 = rg0 * fc[k], s1 = rg1 * fc[k];
                const float s2 = rg2 * fc[k], s3 = rg3 * fc[k];
                #pragma unroll
                for (int d = 0; d < 8; ++d) {
                    comp[d] = fmaf(wcm[(0 * 8 + d) * C + c], s0, comp[d]);
                    comp[d] = fmaf(wcm[(1 * 8 + d) * C + c], s1, comp[d]);
                    comp[d] = fmaf(wcm[(2 * 8 + d) * C + c], s2, comp[d]);
                    comp[d] = fmaf(wcm[(3 * 8 + d) * C + c], s3, comp[d]);
                }
            }
            #pragma unroll
            for (int k = 0; k < 16; ++k) lc[k] = ln[k];
        }
    }

    // ===== expand + residual; fea0 read back from LDS (b128) =====
    float* __restrict__ ob = out + bb * (C * OH * OW) + oy * OW + ox;
    {
        const float* __restrict__ myrow = lds + tid * LDS_STRIDE;
        for (int cc = 0; cc < C; cc += 4) {
            const float4 f4 = *(const float4*)(myrow + cc);    // ds_read_b128
            const float fcv[4] = { f4.x, f4.y, f4.z, f4.w };
            #pragma unroll
            for (int k = 0; k < 4; ++k) {
                const int c = cc + k;
                const float* __restrict__ we0 = wex + (0 * C + c) * 8;
                const float* __restrict__ we1 = wex + (1 * C + c) * 8;
                const float* __restrict__ we2 = wex + (2 * C + c) * 8;
                const float* __restrict__ we3 = wex + (3 * C + c) * 8;
                float s0 = 0.0f, s1 = 0.0f, s2 = 0.0f, s3 = 0.0f;
                #pragma unroll
                for (int d = 0; d < 8; ++d) {
                    s0 = fmaf(we0[d], comp[d], s0);
                    s1 = fmaf(we1[d], comp[d], s1);
                    s2 = fmaf(we2[d], comp[d], s2);
                    s3 = fmaf(we3[d], comp[d], s3);
                }
                float acc = fcv[k];
                acc = fmaf(rg0, s0, acc);
                acc = fmaf(rg1, s1, acc);
                acc = fmaf(rg2, s2, acc);
                acc = fmaf(rg3, s3, acc);
                ob[c * (OH * OW)] = acc;
            }
        }
    }
}

extern "C" void kernel_launch(void* const* d_in, const int* in_sizes, int n_in,
                              void* d_out, int out_size, void* d_ws, size_t ws_size,
                              hipStream_t stream) {
    const float* x   = (const float*)d_in[0];
    const float* wcm = (const float*)d_in[1];
    const float* wex = (const float*)d_in[2];
    const float* w1  = (const float*)d_in[3];
    const float* b1  = (const float*)d_in[4];
    const float* w2  = (const float*)d_in[5];
    const float* b2  = (const float*)d_in[6];
    const float* wr  = (const float*)d_in[7];
    const float* br  = (const float*)d_in[8];
    const float* wo  = (const float*)d_in[9];
    const float* bo  = (const float*)d_in[10];
    float* out = (float*)d_out;

    const int total = BATCH * OH * OW;           // 131072 pixels
    const int blocks = total / BLK;              // 1024 blocks of 128
    scab_kernel<<<blocks, BLK, 0, stream>>>(x, wcm, wex, w1, b1, w2, b2,
                                            wr, br, wo, bo, out);
}

// Round 5
// 176.256 us; speedup vs baseline: 1.2154x; 1.2154x over previous
//
#include <hip/hip_runtime.h>
#include <math.h>

// Fixed problem dims from setup_inputs()
#define BATCH 2
#define C 64
#define HIN 128
#define WIN 128
#define HW (HIN * WIN)
#define OH 256
#define OW 256
#define SCALE 2.0f

#define BLK 256
#define PIX 64   // pixels per block
#define SC 16    // channels per thread-slice (4 slices)

// Round-5 structure: wave-cooperative, 4 slices x 16 channels per pixel.
// Rounds 1-4 proved the allocator spills any ~64-wide per-thread state
// (VGPR stuck at 48-88, VALUBusy 19-35%, 105-360us) and occupancy is
// grid-limited at 8 waves/CU. This round shrinks per-thread state to 16
// accumulators and runs 32 waves/CU (2048 blocks x 256 thr, 16KB LDS).
//  - tid = s*64+p: each wave is one slice -> s wave-uniform -> weights are
//    s_load broadcasts; x loads / out stores coalesced over 64 pixels.
//  - LDS sbuf[c*64+p] (stride 64: 2-way bank alias = free) carries pf,
//    then h1, then head partials, then comp partials (barrier-separated).
//  - convs in accumulator form: 64 LDS reads + 1024 FMA per conv per thread.

__device__ __forceinline__ void bilin_setup(float gx, float gy,
    int& i00, int& i10, int& i01, int& i11,
    float& w00, float& w10, float& w01, float& w11)
{
    const float fx = ((gx + 1.0f) * WIN - 1.0f) * 0.5f;
    const float fy = ((gy + 1.0f) * HIN - 1.0f) * 0.5f;
    const float x0 = floorf(fx), y0 = floorf(fy);
    const float wx1 = fx - x0, wx0 = 1.0f - wx1;
    const float wy1 = fy - y0, wy0 = 1.0f - wy1;
    const float x1 = x0 + 1.0f, y1 = y0 + 1.0f;
    const bool vx0 = (x0 >= 0.0f) && (x0 <= (float)(WIN - 1));
    const bool vx1 = (x1 >= 0.0f) && (x1 <= (float)(WIN - 1));
    const bool vy0 = (y0 >= 0.0f) && (y0 <= (float)(HIN - 1));
    const bool vy1 = (y1 >= 0.0f) && (y1 <= (float)(HIN - 1));
    const int xi0 = (int)fminf(fmaxf(x0, 0.0f), (float)(WIN - 1));
    const int xi1 = (int)fminf(fmaxf(x1, 0.0f), (float)(WIN - 1));
    const int yi0 = (int)fminf(fmaxf(y0, 0.0f), (float)(HIN - 1));
    const int yi1 = (int)fminf(fmaxf(y1, 0.0f), (float)(HIN - 1));
    w00 = wx0 * wy0 * ((vx0 && vy0) ? 1.0f : 0.0f);
    w10 = wx1 * wy0 * ((vx1 && vy0) ? 1.0f : 0.0f);
    w01 = wx0 * wy1 * ((vx0 && vy1) ? 1.0f : 0.0f);
    w11 = wx1 * wy1 * ((vx1 && vy1) ? 1.0f : 0.0f);
    i00 = yi0 * WIN + xi0;  i10 = yi0 * WIN + xi1;
    i01 = yi1 * WIN + xi0;  i11 = yi1 * WIN + xi1;
}

__global__ __launch_bounds__(BLK, 4) void scab_kernel(
    const float* __restrict__ x,    // (B, C, HIN, WIN)
    const float* __restrict__ wcm,  // weight_compress (4, 8, 64)
    const float* __restrict__ wex,  // weight_expand   (4, 64, 8)
    const float* __restrict__ w1,   // (64, 68)
    const float* __restrict__ b1,   // (64)
    const float* __restrict__ w2,   // (64, 64)
    const float* __restrict__ b2,   // (64)
    const float* __restrict__ wr,   // (4, 64)
    const float* __restrict__ br,   // (4)
    const float* __restrict__ wo,   // (2, 64)
    const float* __restrict__ bo,   // (2)
    float* __restrict__ out)        // (B, C, OH, OW)
{
    __shared__ float sbuf[C * PIX];   // 16 KB, multi-purpose (barrier-separated reuse)

    const int tid = threadIdx.x;
    const int p   = tid & 63;                                   // pixel within block
    const int s   = __builtin_amdgcn_readfirstlane(tid >> 6);   // slice == wave id
    const int cb  = s * SC;                                     // my channel base

    const int gp = blockIdx.x * PIX + p;
    const int ox = gp & (OW - 1);
    const int oy = (gp >> 8) & (OH - 1);
    const int bb = gp >> 16;

    // ---- coords channels (match reference exactly) ----
    const float c01 = 1.0f / SCALE;
    const float fh = (oy + 0.5f) / SCALE;
    const float coor_h = fh - floorf(fh + 0.001f) - 0.5f;
    const float fw = (ox + 0.5f) / SCALE;
    const float coor_w = fw - floorf(fw + 0.001f) - 0.5f;

    // ---- base grid ----
    const float gx = ((ox + 0.5f) / SCALE - 0.5f) * (2.0f / (WIN - 1)) - 1.0f;
    const float gy = ((oy + 0.5f) / SCALE - 0.5f) * (2.0f / (HIN - 1)) - 1.0f;

    const float* __restrict__ xb = x + bb * (C * HW);

    // ===== sampling-1: my 16 channels of pre_fea -> LDS =====
    {
        int i00, i10, i01, i11;
        float w00, w10, w01, w11;
        bilin_setup(gx, gy, i00, i10, i01, i11, w00, w10, w01, w11);
        #pragma unroll
        for (int kk = 0; kk < SC; kk += 4) {
            float l[16];
            #pragma unroll
            for (int k = 0; k < 4; ++k) {
                const float* __restrict__ xc = xb + (cb + kk + k) * HW;
                l[4*k+0] = xc[i00]; l[4*k+1] = xc[i10];
                l[4*k+2] = xc[i01]; l[4*k+3] = xc[i11];
            }
            #pragma unroll
            for (int k = 0; k < 4; ++k) {
                const float pf = l[4*k]*w00 + l[4*k+1]*w10 + l[4*k+2]*w01 + l[4*k+3]*w11;
                sbuf[(cb + kk + k) * PIX + p] = pf;
            }
        }
    }
    __syncthreads();

    // ===== conv1 (68 -> my 16 outputs), accumulator form over pf in LDS =====
    float h[SC];
    #pragma unroll
    for (int k = 0; k < SC; ++k) {
        const float* __restrict__ wrow = w1 + (cb + k) * (C + 4);
        h[k] = fmaf(wrow[3], coor_w, fmaf(wrow[2], coor_h,
               fmaf(wrow[1], c01,    fmaf(wrow[0], c01, b1[cb + k]))));
    }
    for (int c = 0; c < C; c += 4) {
        const float p0 = sbuf[(c + 0) * PIX + p];
        const float p1 = sbuf[(c + 1) * PIX + p];
        const float p2 = sbuf[(c + 2) * PIX + p];
        const float p3 = sbuf[(c + 3) * PIX + p];
        #pragma unroll
        for (int k = 0; k < SC; ++k) {
            const float* __restrict__ wrow = w1 + (cb + k) * (C + 4) + 4 + c;  // 16B aligned
            h[k] = fmaf(wrow[0], p0, fmaf(wrow[1], p1,
                   fmaf(wrow[2], p2, fmaf(wrow[3], p3, h[k]))));
        }
    }
    #pragma unroll
    for (int k = 0; k < SC; ++k) h[k] = fmaxf(h[k], 0.0f);

    __syncthreads();                       // all pf reads done
    #pragma unroll
    for (int k = 0; k < SC; ++k) sbuf[(cb + k) * PIX + p] = h[k];
    __syncthreads();

    // ===== conv2 (64 -> my 16 outputs) + head partials =====
    float a[SC];
    #pragma unroll
    for (int k = 0; k < SC; ++k) a[k] = b2[cb + k];
    for (int c = 0; c < C; c += 4) {
        const float h0 = sbuf[(c + 0) * PIX + p];
        const float h1v = sbuf[(c + 1) * PIX + p];
        const float h2v = sbuf[(c + 2) * PIX + p];
        const float h3v = sbuf[(c + 3) * PIX + p];
        #pragma unroll
        for (int k = 0; k < SC; ++k) {
            const float* __restrict__ wrow = w2 + (cb + k) * C + c;            // 16B aligned
            a[k] = fmaf(wrow[0], h0, fmaf(wrow[1], h1v,
                   fmaf(wrow[2], h2v, fmaf(wrow[3], h3v, a[k]))));
        }
    }
    float hx = 0.0f, hy = 0.0f, z0p = 0.0f, z1p = 0.0f, z2p = 0.0f, z3p = 0.0f;
    #pragma unroll
    for (int k = 0; k < SC; ++k) {
        const float e = fmaxf(a[k], 0.0f);
        const int o = cb + k;
        hx  = fmaf(wo[o],         e, hx);
        hy  = fmaf(wo[C + o],     e, hy);
        z0p = fmaf(wr[o],         e, z0p);
        z1p = fmaf(wr[C + o],     e, z1p);
        z2p = fmaf(wr[2 * C + o], e, z2p);
        z3p = fmaf(wr[3 * C + o], e, z3p);
    }

    __syncthreads();                       // all h1 reads done; reuse sbuf for reduction
    sbuf[0 * 256 + s * 64 + p] = hx;
    sbuf[1 * 256 + s * 64 + p] = hy;
    sbuf[2 * 256 + s * 64 + p] = z0p;
    sbuf[3 * 256 + s * 64 + p] = z1p;
    sbuf[4 * 256 + s * 64 + p] = z2p;
    sbuf[5 * 256 + s * 64 + p] = z3p;
    __syncthreads();

    float offx = bo[0], offy = bo[1];
    float z0 = br[0], z1 = br[1], z2 = br[2], z3 = br[3];
    #pragma unroll
    for (int ss = 0; ss < 4; ++ss) {       // fixed order: identical fp32 result in all slices
        offx += sbuf[0 * 256 + ss * 64 + p];
        offy += sbuf[1 * 256 + ss * 64 + p];
        z0   += sbuf[2 * 256 + ss * 64 + p];
        z1   += sbuf[3 * 256 + ss * 64 + p];
        z2   += sbuf[4 * 256 + ss * 64 + p];
        z3   += sbuf[5 * 256 + ss * 64 + p];
    }
    const float rg0 = 1.0f / (1.0f + __expf(-z0));
    const float rg1 = 1.0f / (1.0f + __expf(-z1));
    const float rg2 = 1.0f / (1.0f + __expf(-z2));
    const float rg3 = 1.0f / (1.0f + __expf(-z3));

    // ===== sampling-2 (with offset): my 16 channels of fea0 -> f[], comp partials =====
    float f[SC];
    float cp[8];
    #pragma unroll
    for (int d = 0; d < 8; ++d) cp[d] = 0.0f;
    {
        int j00, j10, j01, j11;
        float v00, v10, v01, v11;
        bilin_setup(gx + offx * (2.0f / (WIN - 1)),
                    gy + offy * (2.0f / (HIN - 1)),
                    j00, j10, j01, j11, v00, v10, v01, v11);
        #pragma unroll
        for (int kk = 0; kk < SC; kk += 4) {
            float l[16];
            #pragma unroll
            for (int k = 0; k < 4; ++k) {
                const float* __restrict__ xc = xb + (cb + kk + k) * HW;
                l[4*k+0] = xc[j00]; l[4*k+1] = xc[j10];
                l[4*k+2] = xc[j01]; l[4*k+3] = xc[j11];
            }
            #pragma unroll
            for (int k = 0; k < 4; ++k) {
                const float fc = l[4*k]*v00 + l[4*k+1]*v10 + l[4*k+2]*v01 + l[4*k+3]*v11;
                f[kk + k] = fc;
                const int c = cb + kk + k;
                const float s0 = rg0 * fc, s1 = rg1 * fc, s2 = rg2 * fc, s3 = rg3 * fc;
                #pragma unroll
                for (int d = 0; d < 8; ++d) {
                    cp[d] = fmaf(wcm[(0 * 8 + d) * C + c], s0, cp[d]);
                    cp[d] = fmaf(wcm[(1 * 8 + d) * C + c], s1, cp[d]);
                    cp[d] = fmaf(wcm[(2 * 8 + d) * C + c], s2, cp[d]);
                    cp[d] = fmaf(wcm[(3 * 8 + d) * C + c], s3, cp[d]);
                }
            }
        }
    }

    __syncthreads();                       // head-partial reads done; reuse sbuf for comp
    #pragma unroll
    for (int d = 0; d < 8; ++d) sbuf[d * 256 + s * 64 + p] = cp[d];
    __syncthreads();

    float comp[8];
    #pragma unroll
    for (int d = 0; d < 8; ++d) {
        float v = sbuf[d * 256 + 0 * 64 + p];
        v += sbuf[d * 256 + 1 * 64 + p];
        v += sbuf[d * 256 + 2 * 64 + p];
        v += sbuf[d * 256 + 3 * 64 + p];
        comp[d] = v;
    }

    // ===== expand + residual for my 16 channels =====
    float* __restrict__ ob = out + bb * (C * OH * OW) + oy * OW + ox;
    #pragma unroll
    for (int k = 0; k < SC; ++k) {
        const int c = cb + k;
        const float* __restrict__ we0 = wex + (0 * C + c) * 8;
        const float* __restrict__ we1 = wex + (1 * C + c) * 8;
        const float* __restrict__ we2 = wex + (2 * C + c) * 8;
        const float* __restrict__ we3 = wex + (3 * C + c) * 8;
        float s0 = 0.0f, s1 = 0.0f, s2 = 0.0f, s3 = 0.0f;
        #pragma unroll
        for (int d = 0; d < 8; ++d) {
            s0 = fmaf(we0[d], comp[d], s0);
            s1 = fmaf(we1[d], comp[d], s1);
            s2 = fmaf(we2[d], comp[d], s2);
            s3 = fmaf(we3[d], comp[d], s3);
        }
        float acc = f[k];
        acc = fmaf(rg0, s0, acc);
        acc = fmaf(rg1, s1, acc);
        acc = fmaf(rg2, s2, acc);
        acc = fmaf(rg3, s3, acc);
        ob[c * (OH * OW)] = acc;           // coalesced: 64 consecutive ox per wave
    }
}

extern "C" void kernel_launch(void* const* d_in, const int* in_sizes, int n_in,
                              void* d_out, int out_size, void* d_ws, size_t ws_size,
                              hipStream_t stream) {
    const float* x   = (const float*)d_in[0];
    const float* wcm = (const float*)d_in[1];
    const float* wex = (const float*)d_in[2];
    const float* w1  = (const float*)d_in[3];
    const float* b1  = (const float*)d_in[4];
    const float* w2  = (const float*)d_in[5];
    const float* b2  = (const float*)d_in[6];
    const float* wr  = (const float*)d_in[7];
    const float* br  = (const float*)d_in[8];
    const float* wo  = (const float*)d_in[9];
    const float* bo  = (const float*)d_in[10];
    float* out = (float*)d_out;

    const int total  = BATCH * OH * OW;    // 131072 pixels
    const int blocks = total / PIX;        // 2048 blocks of 256 threads
    scab_kernel<<<blocks, BLK, 0, stream>>>(x, wcm, wex, w1, b1, w2, b2,
                                            wr, br, wo, bo, out);
}